// Round 3
// baseline (203.289 us; speedup 1.0000x reference)
//
#include <hip/hip_runtime.h>
#include <hip/hip_fp16.h>
#include <math.h>

// Problem constants (fixed by the reference)
#define NE   4
#define NH   64
#define NG   64            // N
#define NB   8
#define NL   8
#define ND   128
#define NDIA 110
#define NK   (NDIA*NB*NG)  // 56320
#define NBN  (NB*NG)       // 512
#define NVOX (NH*NG*NG)    // 262144

typedef int   v2i __attribute__((ext_vector_type(2)));
typedef float v2f __attribute__((ext_vector_type(2)));

// Kernel 1: rotate grid_concentration (bilinear, zero-pad) + xp overwrite,
// store voxel-major fp16x4 conc_t[v] = {conc[e=0..3, v]} (8 B/voxel, 2 MB table
// -> L2-resident; the P streams are marked non-temporal in k_rays so they
// don't evict it).
__global__ __launch_bounds__(256) void k_rotate(
    const float* __restrict__ grid, const float* __restrict__ xp,
    const float* __restrict__ theta_ls, const int* __restrict__ tidx,
    const int* __restrict__ pscal, uint2* __restrict__ conc_t)
{
  int v = blockIdx.x * 256 + threadIdx.x;          // voxel id, 0..NVOX-1
  int h = v >> 12;
  int i = (v >> 6) & 63;                            // row
  int j = v & 63;                                   // col
  float theta = theta_ls[tidx[0]];
  float st, ct;
  sincosf(theta, &st, &ct);
  const float c = 31.5f;                            // (N-1)/2
  float x = (float)j - c, y = (float)i - c;
  float xs = ct * x - st * y + c;
  float ys = st * x + ct * y + c;
  float x0f = floorf(xs), y0f = floorf(ys);
  int x0 = (int)x0f, y0 = (int)y0f;
  float wx = xs - x0f, wy = ys - y0f;
  int x1 = x0 + 1, y1 = y0 + 1;
  bool vx0 = (unsigned)x0 < 64u, vx1 = (unsigned)x1 < 64u;
  bool vy0 = (unsigned)y0 < 64u, vy1 = (unsigned)y1 < 64u;
  float w00 = (vy0 && vx0) ? (1.f - wy) * (1.f - wx) : 0.f;
  float w01 = (vy0 && vx1) ? (1.f - wy) * wx         : 0.f;
  float w10 = (vy1 && vx0) ? wy * (1.f - wx)         : 0.f;
  float w11 = (vy1 && vx1) ? wy * wx                 : 0.f;
  int xc0 = min(max(x0, 0), 63), xc1 = min(max(x1, 0), 63);
  int yc0 = min(max(y0, 0), 63), yc1 = min(max(y1, 0), 63);
  int i00 = yc0 * 64 + xc0, i01 = yc0 * 64 + xc1;
  int i10 = yc1 * 64 + xc0, i11 = yc1 * 64 + xc1;
  int hn = (h << 6) | i;                            // flattened H*N row
  int pb = 8 * pscal[0];                            // B*p
  bool ov = (hn >= pb) && (hn < pb + 8);
  int xoff = ov ? (((hn - pb) << 6) | j) : 0;
  float o[4];
#pragma unroll
  for (int e = 0; e < NE; e++) {
    const float* g = grid + (((e << 6) + h) << 12); // (e*H + h)*N*N
    float val = w00 * g[i00] + w01 * g[i01] + w10 * g[i10] + w11 * g[i11];
    if (ov) val = xp[(e << 9) + xoff];              // xp[e, hn-pb, j]
    o[e] = val;
  }
  __half2 h01 = __floats2half2_rn(o[0], o[1]);
  __half2 h23 = __floats2half2_rn(o[2], o[3]);
  uint2 u;
  u.x = *(unsigned int*)&h01;
  u.y = *(unsigned int*)&h23;
  conc_t[v] = u;
}

// Kernel 2: per (d, v) ray sums over 110 path entries (8 lanes cooperate,
// 14x7 + 12 split), then each of the 8 lanes handles one line l:
// expval[d][l][v] = exp(-sum_e FL[e,l]*per_ray[e]).
// P_idx / P_len are streamed once -> non-temporal loads (keep conc_t in L2).
__global__ __launch_bounds__(256) void k_rays(
    const int* __restrict__ P_idx, const float* __restrict__ P_len,
    const uint2* __restrict__ conc_t, const float* __restrict__ FLp,
    float* __restrict__ expval)
{
  int q = threadIdx.x & 7;                          // eighth of the ray / line id
  int ray = (blockIdx.x << 5) | (threadIdx.x >> 3); // (d,v) id, 0..65535
  int d = ray >> 9;
  int v = ray & 511;
  // per-lane FL coefficients for line l = q
  float fl0 = FLp[q], fl1 = FLp[8 + q], fl2 = FLp[16 + q], fl3 = FLp[24 + q];
  size_t off = (size_t)d * NK + (size_t)v * NDIA + (size_t)(q * 14);
  const v2i* ip = (const v2i*)(P_idx + off);
  const v2f* lp = (const v2f*)(P_len + off);
  int cnt = (q == 7) ? 6 : 7;                       // int2 pairs
  float a0 = 0.f, a1 = 0.f, a2 = 0.f, a3 = 0.f;
  for (int t = 0; t < cnt; t++) {
    v2i id = __builtin_nontemporal_load(ip + t);
    v2f ln = __builtin_nontemporal_load(lp + t);
    uint2 u0 = conc_t[id.x];
    uint2 u1 = conc_t[id.y];
    float2 c01 = __half22float2(*(__half2*)&u0.x);
    float2 c23 = __half22float2(*(__half2*)&u0.y);
    a0 += c01.x * ln.x; a1 += c01.y * ln.x;
    a2 += c23.x * ln.x; a3 += c23.y * ln.x;
    float2 d01 = __half22float2(*(__half2*)&u1.x);
    float2 d23 = __half22float2(*(__half2*)&u1.y);
    a0 += d01.x * ln.y; a1 += d01.y * ln.y;
    a2 += d23.x * ln.y; a3 += d23.y * ln.y;
  }
  // combine the 8 cooperating lanes (adjacent in the wave)
  a0 += __shfl_xor(a0, 1); a1 += __shfl_xor(a1, 1);
  a2 += __shfl_xor(a2, 1); a3 += __shfl_xor(a3, 1);
  a0 += __shfl_xor(a0, 2); a1 += __shfl_xor(a1, 2);
  a2 += __shfl_xor(a2, 2); a3 += __shfl_xor(a3, 2);
  a0 += __shfl_xor(a0, 4); a1 += __shfl_xor(a1, 4);
  a2 += __shfl_xor(a2, 4); a3 += __shfl_xor(a3, 4);
  float s = fl0 * a0 + fl1 * a1 + fl2 * a2 + fl3 * a3;
  expval[((size_t)d << 12) + (q << 9) + v] = __expf(-s);
}

// Kernel 3: SA = mean_d expval; apply probe attenuation (shfl prefix scan) and
// fl_map, reduce over n. Block = (l,b); 256 threads = 4 d-chunks x 64 n.
__global__ __launch_bounds__(256) void k_final(
    const float* __restrict__ expval, const float* __restrict__ xp,
    const float* __restrict__ attCS, const float* __restrict__ dfl,
    const float* __restrict__ scm, const float* __restrict__ pcts,
    const int* __restrict__ l2e, float* __restrict__ out)
{
  __shared__ float red[256];
  int l = blockIdx.x >> 3;
  int b = blockIdx.x & 7;
  int n = threadIdx.x & 63;
  int dc = threadIdx.x >> 6;                        // d-chunk 0..3
  int v = (b << 6) | n;
  const float* ep = expval + (l << 9) + v;
  float s = 0.f;
#pragma unroll
  for (int t = 0; t < 32; t++) s += ep[(size_t)(dc * 32 + t) << 12];
  red[threadIdx.x] = s;
  __syncthreads();
  if (dc == 0) {
    float sa = red[n] + red[n + 64] + red[n + 128] + red[n + 192];
    float dx = scm[0] * (1.0f / 64.0f);
    float pc = pcts[0];
    float lac = attCS[0] * xp[v] + attCS[1] * xp[512 + v]
              + attCS[2] * xp[1024 + v] + attCS[3] * xp[1536 + v];
    // inclusive prefix scan of lac over the 64 lanes (n)
    float inc = lac;
#pragma unroll
    for (int ofs = 1; ofs < 64; ofs <<= 1) {
      float t = __shfl_up(inc, ofs, 64);
      if (n >= ofs) inc += t;
    }
    float pre = inc - lac;                          // exclusive prefix
    float att = __expf(-dx * pre);
    float val = pc * att * xp[(l2e[l] << 9) + v] * dfl[l] * sa * (1.0f / 128.0f);
#pragma unroll
    for (int ofs = 32; ofs > 0; ofs >>= 1) val += __shfl_down(val, ofs, 64);
    if (n == 0) out[(l << 3) + b] = val;
    if (l == 0 && n == 63) out[64 + b] = pc * __expf(-dx * inc);
  }
}

extern "C" void kernel_launch(void* const* d_in, const int* in_sizes, int n_in,
                              void* d_out, int out_size, void* d_ws, size_t ws_size,
                              hipStream_t stream) {
  const float* grid_c   = (const float*)d_in[0];   // (E,H,N,N)
  const float* xp       = (const float*)d_in[1];   // (E,B,N)
  const float* theta_ls = (const float*)d_in[2];   // (16,)
  const float* attCS    = (const float*)d_in[3];   // (E,)
  const float* FLp      = (const float*)d_in[4];   // (E,L)
  const float* dfl      = (const float*)d_in[5];   // (L,)
  const float* P_len    = (const float*)d_in[6];   // (D,K)
  const float* scm      = (const float*)d_in[7];   // scalar
  const float* pcts     = (const float*)d_in[8];   // scalar
  const int*   l2e      = (const int*)d_in[9];     // (L,)
  const int*   P_idx    = (const int*)d_in[10];    // (D,K)
  const int*   tidx     = (const int*)d_in[11];    // scalar
  const int*   pscal    = (const int*)d_in[12];    // scalar
  float* out = (float*)d_out;                      // 64 (out1) + 8 (out2)

  uint2* conc_t = (uint2*)d_ws;                    // NVOX * 8 B = 2 MB
  float* expval = (float*)((char*)d_ws + (size_t)NVOX * 8); // D*L*BN floats = 2 MB

  k_rotate<<<NVOX / 256, 256, 0, stream>>>(grid_c, xp, theta_ls, tidx, pscal, conc_t);
  k_rays<<<(ND * NBN) / 32, 256, 0, stream>>>(P_idx, P_len, conc_t, FLp, expval);
  k_final<<<NL * NB, 256, 0, stream>>>(expval, xp, attCS, dfl, scm, pcts, l2e, out);
}

// Round 4
// 147.025 us; speedup vs baseline: 1.3827x; 1.3827x over previous
//
#include <hip/hip_runtime.h>
#include <math.h>

// Problem constants (fixed by the reference)
#define NE   4
#define NH   64
#define NG   64            // N
#define NB   8
#define NL   8
#define ND   128
#define NDIA 110
#define NK   (NDIA*NB*NG)  // 56320
#define NBN  (NB*NG)       // 512
#define NVOX (NH*NG*NG)    // 262144

typedef int   v2i __attribute__((ext_vector_type(2)));
typedef float v2f __attribute__((ext_vector_type(2)));

// Kernel 1: rotate grid_concentration (bilinear, zero-pad) + xp overwrite,
// store voxel-major OCP fp8(e4m3)x4: conc_t[v] = pack{conc[e=0..3, v]}.
// 4 B/voxel -> 1 MB table, L2-resident under the P-stream pressure.
__global__ __launch_bounds__(256) void k_rotate(
    const float* __restrict__ grid, const float* __restrict__ xp,
    const float* __restrict__ theta_ls, const int* __restrict__ tidx,
    const int* __restrict__ pscal, unsigned int* __restrict__ conc_t)
{
  int v = blockIdx.x * 256 + threadIdx.x;          // voxel id, 0..NVOX-1
  int h = v >> 12;
  int i = (v >> 6) & 63;                            // row
  int j = v & 63;                                   // col
  float theta = theta_ls[tidx[0]];
  float st, ct;
  sincosf(theta, &st, &ct);
  const float c = 31.5f;                            // (N-1)/2
  float x = (float)j - c, y = (float)i - c;
  float xs = ct * x - st * y + c;
  float ys = st * x + ct * y + c;
  float x0f = floorf(xs), y0f = floorf(ys);
  int x0 = (int)x0f, y0 = (int)y0f;
  float wx = xs - x0f, wy = ys - y0f;
  int x1 = x0 + 1, y1 = y0 + 1;
  bool vx0 = (unsigned)x0 < 64u, vx1 = (unsigned)x1 < 64u;
  bool vy0 = (unsigned)y0 < 64u, vy1 = (unsigned)y1 < 64u;
  float w00 = (vy0 && vx0) ? (1.f - wy) * (1.f - wx) : 0.f;
  float w01 = (vy0 && vx1) ? (1.f - wy) * wx         : 0.f;
  float w10 = (vy1 && vx0) ? wy * (1.f - wx)         : 0.f;
  float w11 = (vy1 && vx1) ? wy * wx                 : 0.f;
  int xc0 = min(max(x0, 0), 63), xc1 = min(max(x1, 0), 63);
  int yc0 = min(max(y0, 0), 63), yc1 = min(max(y1, 0), 63);
  int i00 = yc0 * 64 + xc0, i01 = yc0 * 64 + xc1;
  int i10 = yc1 * 64 + xc0, i11 = yc1 * 64 + xc1;
  int hn = (h << 6) | i;                            // flattened H*N row
  int pb = 8 * pscal[0];                            // B*p
  bool ov = (hn >= pb) && (hn < pb + 8);
  int xoff = ov ? (((hn - pb) << 6) | j) : 0;
  float o[4];
#pragma unroll
  for (int e = 0; e < NE; e++) {
    const float* g = grid + (((e << 6) + h) << 12); // (e*H + h)*N*N
    float val = w00 * g[i00] + w01 * g[i01] + w10 * g[i10] + w11 * g[i11];
    if (ov) val = xp[(e << 9) + xoff];              // xp[e, hn-pb, j]
    o[e] = val;
  }
  unsigned int packed = 0;
  packed = __builtin_amdgcn_cvt_pk_fp8_f32(o[0], o[1], packed, false); // low word
  packed = __builtin_amdgcn_cvt_pk_fp8_f32(o[2], o[3], packed, true);  // high word
  conc_t[v] = packed;
}

// Kernel 2: per (d, v) ray sums over 110 path entries (8 lanes cooperate,
// 14x7 + 12 split), then each of the 8 lanes handles one line l:
// expval[d][l][v] = exp(-sum_e FL[e,l]*per_ray[e]).
__global__ __launch_bounds__(256) void k_rays(
    const int* __restrict__ P_idx, const float* __restrict__ P_len,
    const unsigned int* __restrict__ conc_t, const float* __restrict__ FLp,
    float* __restrict__ expval)
{
  int q = threadIdx.x & 7;                          // eighth of the ray / line id
  int ray = (blockIdx.x << 5) | (threadIdx.x >> 3); // (d,v) id, 0..65535
  int d = ray >> 9;
  int v = ray & 511;
  // per-lane FL coefficients for line l = q
  float fl0 = FLp[q], fl1 = FLp[8 + q], fl2 = FLp[16 + q], fl3 = FLp[24 + q];
  size_t off = (size_t)d * NK + (size_t)v * NDIA + (size_t)(q * 14);
  const v2i* ip = (const v2i*)(P_idx + off);
  const v2f* lp = (const v2f*)(P_len + off);
  int cnt = (q == 7) ? 6 : 7;                       // int2 pairs (tail lane: 12 entries)
  float a0 = 0.f, a1 = 0.f, a2 = 0.f, a3 = 0.f;
#pragma unroll
  for (int t = 0; t < 7; t++) {
    if (t < cnt) {
      v2i id = ip[t];
      v2f ln = lp[t];
      unsigned int u0 = conc_t[id.x];
      unsigned int u1 = conc_t[id.y];
      v2f c01 = __builtin_amdgcn_cvt_pk_f32_fp8(u0, false);
      v2f c23 = __builtin_amdgcn_cvt_pk_f32_fp8(u0, true);
      a0 += c01.x * ln.x; a1 += c01.y * ln.x;
      a2 += c23.x * ln.x; a3 += c23.y * ln.x;
      v2f d01 = __builtin_amdgcn_cvt_pk_f32_fp8(u1, false);
      v2f d23 = __builtin_amdgcn_cvt_pk_f32_fp8(u1, true);
      a0 += d01.x * ln.y; a1 += d01.y * ln.y;
      a2 += d23.x * ln.y; a3 += d23.y * ln.y;
    }
  }
  // combine the 8 cooperating lanes (adjacent in the wave)
  a0 += __shfl_xor(a0, 1); a1 += __shfl_xor(a1, 1);
  a2 += __shfl_xor(a2, 1); a3 += __shfl_xor(a3, 1);
  a0 += __shfl_xor(a0, 2); a1 += __shfl_xor(a1, 2);
  a2 += __shfl_xor(a2, 2); a3 += __shfl_xor(a3, 2);
  a0 += __shfl_xor(a0, 4); a1 += __shfl_xor(a1, 4);
  a2 += __shfl_xor(a2, 4); a3 += __shfl_xor(a3, 4);
  float s = fl0 * a0 + fl1 * a1 + fl2 * a2 + fl3 * a3;
  expval[((size_t)d << 12) + (q << 9) + v] = __expf(-s);
}

// Kernel 3: SA = mean_d expval; apply probe attenuation (shfl prefix scan) and
// fl_map, reduce over n. Block = (l,b); 256 threads = 4 d-chunks x 64 n.
__global__ __launch_bounds__(256) void k_final(
    const float* __restrict__ expval, const float* __restrict__ xp,
    const float* __restrict__ attCS, const float* __restrict__ dfl,
    const float* __restrict__ scm, const float* __restrict__ pcts,
    const int* __restrict__ l2e, float* __restrict__ out)
{
  __shared__ float red[256];
  int l = blockIdx.x >> 3;
  int b = blockIdx.x & 7;
  int n = threadIdx.x & 63;
  int dc = threadIdx.x >> 6;                        // d-chunk 0..3
  int v = (b << 6) | n;
  const float* ep = expval + (l << 9) + v;
  float s = 0.f;
#pragma unroll
  for (int t = 0; t < 32; t++) s += ep[(size_t)(dc * 32 + t) << 12];
  red[threadIdx.x] = s;
  __syncthreads();
  if (dc == 0) {
    float sa = red[n] + red[n + 64] + red[n + 128] + red[n + 192];
    float dx = scm[0] * (1.0f / 64.0f);
    float pc = pcts[0];
    float lac = attCS[0] * xp[v] + attCS[1] * xp[512 + v]
              + attCS[2] * xp[1024 + v] + attCS[3] * xp[1536 + v];
    // inclusive prefix scan of lac over the 64 lanes (n)
    float inc = lac;
#pragma unroll
    for (int ofs = 1; ofs < 64; ofs <<= 1) {
      float t = __shfl_up(inc, ofs, 64);
      if (n >= ofs) inc += t;
    }
    float pre = inc - lac;                          // exclusive prefix
    float att = __expf(-dx * pre);
    float val = pc * att * xp[(l2e[l] << 9) + v] * dfl[l] * sa * (1.0f / 128.0f);
#pragma unroll
    for (int ofs = 32; ofs > 0; ofs >>= 1) val += __shfl_down(val, ofs, 64);
    if (n == 0) out[(l << 3) + b] = val;
    if (l == 0 && n == 63) out[64 + b] = pc * __expf(-dx * inc);
  }
}

extern "C" void kernel_launch(void* const* d_in, const int* in_sizes, int n_in,
                              void* d_out, int out_size, void* d_ws, size_t ws_size,
                              hipStream_t stream) {
  const float* grid_c   = (const float*)d_in[0];   // (E,H,N,N)
  const float* xp       = (const float*)d_in[1];   // (E,B,N)
  const float* theta_ls = (const float*)d_in[2];   // (16,)
  const float* attCS    = (const float*)d_in[3];   // (E,)
  const float* FLp      = (const float*)d_in[4];   // (E,L)
  const float* dfl      = (const float*)d_in[5];   // (L,)
  const float* P_len    = (const float*)d_in[6];   // (D,K)
  const float* scm      = (const float*)d_in[7];   // scalar
  const float* pcts     = (const float*)d_in[8];   // scalar
  const int*   l2e      = (const int*)d_in[9];     // (L,)
  const int*   P_idx    = (const int*)d_in[10];    // (D,K)
  const int*   tidx     = (const int*)d_in[11];    // scalar
  const int*   pscal    = (const int*)d_in[12];    // scalar
  float* out = (float*)d_out;                      // 64 (out1) + 8 (out2)

  unsigned int* conc_t = (unsigned int*)d_ws;      // NVOX * 4 B = 1 MB
  float* expval = (float*)((char*)d_ws + (size_t)NVOX * 4); // D*L*BN floats = 2 MB

  k_rotate<<<NVOX / 256, 256, 0, stream>>>(grid_c, xp, theta_ls, tidx, pscal, conc_t);
  k_rays<<<(ND * NBN) / 32, 256, 0, stream>>>(P_idx, P_len, conc_t, FLp, expval);
  k_final<<<NL * NB, 256, 0, stream>>>(expval, xp, attCS, dfl, scm, pcts, l2e, out);
}